// Round 14
// baseline (3027.365 us; speedup 1.0000x reference)
//
#include <hip/hip_runtime.h>

#define BB 4
#define NN 16384
#define CC 64
#define NPOINT 1024
#define NSAMPLE 32

#define FPS_T 1024
#define NCHUNK 256          // 64 points per chunk
#define NCELL 4096          // 16^3 Morton cells
#define GRID_TOTAL 200      // 4 fps + 196 consumer blocks (<= 256 CUs)

#define REPEAT16(M) M(0) M(1) M(2) M(3) M(4) M(5) M(6) M(7) \
                    M(8) M(9) M(10) M(11) M(12) M(13) M(14) M(15)

// ---------------------------------------------------------------------------
// Fused cooperative kernel.
// Blocks 0..3  : R11-exact pruned FPS (validated 1.38 us/iter optimum), with
//                per-iteration centroid publication: rotating publisher wave
//                (it&15, lane 0) stores coords to new_xyz via agent-scope
//                atomics then releases progress[b]=it+1. vmcnt drain before
//                the barrier is amortized 1/16 per wave.
// Blocks 4..199: persistent consumers. Each round = 8 queries (2 waves each):
//                spin on progress[b] (acquire, 1 thread + s_sleep), agent-
//                load centroid, wave-0-of-pair ballq -> LDS gidx, gather
//                feats, MLP1 (w1 rows in regs, LDS broadcast reads), MLP2 +
//                per-thread max over all 32 samples, store new_points.
// Exactness: fps + ballq blocks use fp contract(off) + reference op order;
// centroid consumed by ballq is the bit-exact published value. MLP uses FMA
// (reference einsum -> GEMM, accumulation order free).
// ---------------------------------------------------------------------------
__global__ __launch_bounds__(FPS_T, 4) void fused_kernel(
        const float* __restrict__ xyz, const float* __restrict__ points,
        const float* __restrict__ w1,  const float* __restrict__ b1,
        const float* __restrict__ w2,  const float* __restrict__ b2,
        float* __restrict__ new_xyz,   float* __restrict__ new_points,
        float4* __restrict__ sorted,   unsigned* __restrict__ prog) {
    extern __shared__ char smem_raw[];

    if (blockIdx.x < 4) {
        // ================= FPS producer (R11-exact + publication) =========
        #pragma clang fp contract(off)
        float2* sxy  = (float2*)smem_raw;                         // 131072 B
        int*    hist = (int*)(smem_raw + 131072);                 // 16384 B
        float4* wbc  = (float4*)(smem_raw + 147456);              // [2][16]
        unsigned long long* slot = (unsigned long long*)(smem_raw + 147968); // [4]
        int*    wsum = (int*)(smem_raw + 148000);                 // [16]

        const int b    = blockIdx.x;
        const int tid  = threadIdx.x;
        const int lane = tid & 63;
        const int wv   = tid >> 6;                  // 0..15
        const float* bx = xyz + (size_t)b * NN * 3;
        float4* sb = sorted + (size_t)b * NN;
        float* outg = new_xyz + (size_t)b * NPOINT * 3;

        // ---------- phase 0a: histogram ----------
        #pragma unroll
        for (int j = 0; j < 4; ++j) hist[j * FPS_T + tid] = 0;
        __syncthreads();

        #pragma unroll
        for (int j = 0; j < 16; ++j) {
            const int p = j * FPS_T + tid;
            const float x = bx[p * 3 + 0], y = bx[p * 3 + 1], z = bx[p * 3 + 2];
            int cx = (int)(x * 16.0f); cx = cx > 15 ? 15 : (cx < 0 ? 0 : cx);
            int cy = (int)(y * 16.0f); cy = cy > 15 ? 15 : (cy < 0 ? 0 : cy);
            int cz = (int)(z * 16.0f); cz = cz > 15 ? 15 : (cz < 0 ? 0 : cz);
            int code = 0;
            #pragma unroll
            for (int i = 0; i < 4; ++i)
                code |= (((cx >> i) & 1) << (3 * i)) |
                        (((cy >> i) & 1) << (3 * i + 1)) |
                        (((cz >> i) & 1) << (3 * i + 2));
            atomicAdd(&hist[code], 1);
        }
        __syncthreads();

        // ---------- phase 0b: exclusive scan ----------
        {
            const int h0 = hist[4 * tid + 0], h1 = hist[4 * tid + 1];
            const int h2 = hist[4 * tid + 2], h3 = hist[4 * tid + 3];
            const int s  = h0 + h1 + h2 + h3;
            int v = s;
            #pragma unroll
            for (int o = 1; o < 64; o <<= 1) {
                const int u = __shfl_up(v, o, 64);
                if (lane >= o) v += u;
            }
            if (lane == 63) wsum[wv] = v;
            __syncthreads();
            int base = 0;
            for (int w = 0; w < wv; ++w) base += wsum[w];
            const int e0 = base + v - s;
            hist[4 * tid + 0] = e0;
            hist[4 * tid + 1] = e0 + h0;
            hist[4 * tid + 2] = e0 + h0 + h1;
            hist[4 * tid + 3] = e0 + h0 + h1 + h2;
        }
        __syncthreads();

        // ---------- phase 0c: scatter to global sb AND LDS sxy ----------
        #pragma unroll
        for (int j = 0; j < 16; ++j) {
            const int p = j * FPS_T + tid;
            const float x = bx[p * 3 + 0], y = bx[p * 3 + 1], z = bx[p * 3 + 2];
            int cx = (int)(x * 16.0f); cx = cx > 15 ? 15 : (cx < 0 ? 0 : cx);
            int cy = (int)(y * 16.0f); cy = cy > 15 ? 15 : (cy < 0 ? 0 : cy);
            int cz = (int)(z * 16.0f); cz = cz > 15 ? 15 : (cz < 0 ? 0 : cz);
            int code = 0;
            #pragma unroll
            for (int i = 0; i < 4; ++i)
                code |= (((cx >> i) & 1) << (3 * i)) |
                        (((cy >> i) & 1) << (3 * i + 1)) |
                        (((cz >> i) & 1) << (3 * i + 2));
            const int slotg = atomicAdd(&hist[code], 1);
            sb[slotg]  = make_float4(x, y, z, __int_as_float(p));
            sxy[slotg] = make_float2(x, y);
        }
        __syncthreads();

        // ---------- phase 0d: per-chunk AABB + z/key preload ----------
#define DECLZ(k) float z##k; unsigned long long key##k;
        REPEAT16(DECLZ)
#undef DECLZ
        float abx0 = 0.f, aby0 = 0.f, abz0 = 0.f, abx1 = 0.f, aby1 = 0.f, abz1 = 0.f;

#define AABBPRE(k) { const int g = wv + ((k) << 4);                       \
        const float4 pt = sb[(g << 6) + lane];                            \
        z##k = pt.z;                                                      \
        key##k = (((unsigned long long)__float_as_uint(1e10f)) << 32) |   \
                 ((unsigned long long)(0x3FFFu -                          \
                        (unsigned)__float_as_int(pt.w)) << 4);            \
        float mnx = pt.x, mxx = pt.x, mny = pt.y, mxy = pt.y,             \
              mnz = pt.z, mxz = pt.z;                                     \
        _Pragma("unroll")                                                 \
        for (int m = 32; m >= 1; m >>= 1) {                               \
            mnx = fminf(mnx, __shfl_xor(mnx, m, 64));                     \
            mxx = fmaxf(mxx, __shfl_xor(mxx, m, 64));                     \
            mny = fminf(mny, __shfl_xor(mny, m, 64));                     \
            mxy = fmaxf(mxy, __shfl_xor(mxy, m, 64));                     \
            mnz = fminf(mnz, __shfl_xor(mnz, m, 64));                     \
            mxz = fmaxf(mxz, __shfl_xor(mxz, m, 64));                     \
        }                                                                 \
        if (lane == (k)) { abx0 = mnx; abx1 = mxx; aby0 = mny;            \
                           aby1 = mxy; abz0 = mnz; abz1 = mxz; } }
        REPEAT16(AABBPRE)
#undef AABBPRE
        if (tid < 4) slot[tid] = 0ull;
        __syncthreads();

        // ---------- main loop: ONE barrier per iteration ----------
        unsigned long long bkey = 0ull;
        int bestk = 0;
        int holder_ln = 0;
        float hx = 0.f, hy = 0.f, hz = 0.f;
        float cub = 1e10f;

        float ccx = bx[0], ccy = bx[1], ccz = bx[2];
        float prev_wd = 1e10f;

        for (int it = 0; it < NPOINT; ++it) {
            asm volatile("" : "+v"(z0), "+v"(z1), "+v"(z2),  "+v"(z3),
                              "+v"(z4), "+v"(z5), "+v"(z6),  "+v"(z7),
                              "+v"(z8), "+v"(z9), "+v"(z10), "+v"(z11),
                              "+v"(z12), "+v"(z13), "+v"(z14), "+v"(z15));

            // rotating publisher: coords + release progress
            if (wv == (it & 15) && lane == 0) {
                unsigned* og = (unsigned*)(outg + it * 3);
                __hip_atomic_store(og + 0, __float_as_uint(ccx),
                                   __ATOMIC_RELAXED, __HIP_MEMORY_SCOPE_AGENT);
                __hip_atomic_store(og + 1, __float_as_uint(ccy),
                                   __ATOMIC_RELAXED, __HIP_MEMORY_SCOPE_AGENT);
                __hip_atomic_store(og + 2, __float_as_uint(ccz),
                                   __ATOMIC_RELAXED, __HIP_MEMORY_SCOPE_AGENT);
                __hip_atomic_store(&prog[b], (unsigned)(it + 1),
                                   __ATOMIC_RELEASE, __HIP_MEMORY_SCOPE_AGENT);
            }

            // --- AABB prune + cub maintenance ---
            bool active = false;
            if (lane < 16) {
                const float dxl = fmaxf(fmaxf(abx0 - ccx, ccx - abx1), 0.0f);
                const float dyl = fmaxf(fmaxf(aby0 - ccy, ccy - aby1), 0.0f);
                const float dzl = fmaxf(fmaxf(abz0 - ccz, ccz - abz1), 0.0f);
                const float mind2 = dxl * dxl + dyl * dyl + dzl * dzl;
                const float bound = fminf(prev_wd, cub);
                active = !(mind2 > bound * 1.001f);
                if (active) {
                    const float dxm = fmaxf(ccx - abx0, abx1 - ccx);
                    const float dym = fmaxf(ccy - aby0, aby1 - ccy);
                    const float dzm = fmaxf(ccz - abz0, abz1 - ccz);
                    const float maxd2 = dxm * dxm + dym * dym + dzm * dzm;
                    cub = fminf(cub, maxd2);
                }
            }
            const unsigned amask = (unsigned)(__ballot(active) & 0xFFFFull);

            bool lredo = false;
#define UPD(k) if (amask & (1u << (k))) {                                 \
                const int g = wv + ((k) << 4);                            \
                const float2 xy = sxy[(g << 6) + lane];                   \
                const float dx = xy.x - ccx;                              \
                const float dy = xy.y - ccy;                              \
                const float dz = z##k - ccz;                              \
                const float t  = (dx * dx + dy * dy) + dz * dz;           \
                const float dold = __uint_as_float((unsigned)(key##k >> 32)); \
                if (t < dold) {                                           \
                    key##k = (((unsigned long long)__float_as_uint(t)) << 32) \
                             | (key##k & 0xFFFFFFFFull);                  \
                    lredo |= ((k) == bestk);                              \
                }                                                         \
            }
            if (amask & 0x000Fu) { UPD(0)  UPD(1)  UPD(2)  UPD(3)  }
            if (amask & 0x00F0u) { UPD(4)  UPD(5)  UPD(6)  UPD(7)  }
            if (amask & 0x0F00u) { UPD(8)  UPD(9)  UPD(10) UPD(11) }
            if (amask & 0xF000u) { UPD(12) UPD(13) UPD(14) UPD(15) }
#undef UPD

            if (lredo) {
                bkey = 0ull; bestk = 0;
#define LM(k) if (key##k > bkey) { bkey = key##k; bestk = (k); }
                REPEAT16(LM)
#undef LM
            }

            const unsigned long long rb = __ballot(lredo);
            if ((rb >> holder_ln) & 1ull) {
                unsigned long long m = bkey;
                #pragma unroll
                for (int s = 32; s >= 1; s >>= 1) {
                    const unsigned long long o = __shfl_xor(m, s, 64);
                    m = o > m ? o : m;
                }
                holder_ln = __ffsll((long long)__ballot(bkey == m)) - 1;
                if (lane == holder_ln) {
                    const float2 xy = sxy[((wv + (bestk << 4)) << 6) + lane];
                    float zz = z0;
#define ZS(k) zz = (bestk == (k)) ? z##k : zz;
                    REPEAT16(ZS)
#undef ZS
                    hx = xy.x; hy = xy.y; hz = zz;
                }
            }

            if (lane == holder_ln) {
                wbc[(it & 1) * 16 + wv] = make_float4(hx, hy, hz, 0.0f);
                atomicMax(&slot[it & 3], bkey | (unsigned long long)wv);
            }
            if (tid == 0) slot[(it + 1) & 3] = 0ull;
            __syncthreads();

            const unsigned long long wk = slot[it & 3];
            prev_wd = __uint_as_float((unsigned)(wk >> 32));
            const int wwv = (int)(wk & 0xFull);
            const float4 wf = wbc[(it & 1) * 16 + wwv];
            ccx = wf.x; ccy = wf.y; ccz = wf.z;
        }
        return;
    }

    // ================= Consumer blocks: ballq + MLP per query =============
    float* feats = (float*)smem_raw;                     // [8][32][68]
    float* h1s   = (float*)(smem_raw + 69632);           // [8][32][64]
    int*   sgidx = (int*)(smem_raw + 135168);            // [8][32]

    const int ci   = blockIdx.x - 4;
    const int NC   = (int)gridDim.x - 4;                 // 196
    const int tid  = threadIdx.x;
    const int lane = tid & 63;
    const int pr   = tid >> 7;                           // pair 0..7
    const int pl   = tid & 127;                          // lane within pair
    const int wi   = (tid >> 6) & 1;                     // wave within pair

    for (int q0 = ci * 8; q0 < BB * NPOINT; q0 += NC * 8) {
        const int b     = q0 >> 10;
        const int maxiq = (q0 + 7) & 1023;

        if (tid == 0) {
            while ((int)__hip_atomic_load(&prog[b], __ATOMIC_ACQUIRE,
                                          __HIP_MEMORY_SCOPE_AGENT) <= maxiq)
                __builtin_amdgcn_s_sleep(10);
        }
        __syncthreads();

        const int q = q0 + pr;
        const unsigned* cg = (const unsigned*)(new_xyz + (size_t)q * 3);
        const float cx = __uint_as_float(__hip_atomic_load(cg + 0,
                __ATOMIC_RELAXED, __HIP_MEMORY_SCOPE_AGENT));
        const float cy = __uint_as_float(__hip_atomic_load(cg + 1,
                __ATOMIC_RELAXED, __HIP_MEMORY_SCOPE_AGENT));
        const float cz = __uint_as_float(__hip_atomic_load(cg + 2,
                __ATOMIC_RELAXED, __HIP_MEMORY_SCOPE_AGENT));

        // --- ballq by the even wave of each pair (exact reference math) ---
        if (wi == 0) {
            #pragma clang fp contract(off)
            const float* bx = xyz + (size_t)b * NN * 3;
            const float rad2 = 0.04f;   // f32(0.2**2), NOT 0.2f*0.2f
            int* out  = sgidx + pr * 32;
            int taken = 0;
            int first = NN - 1;
            for (int chunk = 0; chunk < NN / 64 && taken < NSAMPLE; ++chunk) {
                const int   i  = chunk * 64 + lane;
                const float dx = cx - bx[i * 3 + 0];
                const float dy = cy - bx[i * 3 + 1];
                const float dz = cz - bx[i * 3 + 2];
                const float t  = dx * dx + dy * dy + dz * dz;
                const bool ok  = !(t > rad2);
                const unsigned long long m = __ballot(ok);
                const int cnt = __popcll(m);
                if (taken == 0 && cnt > 0)
                    first = chunk * 64 + (__ffsll((long long)m) - 1);
                if (ok) {
                    const int rank = taken + __popcll(m & ((1ull << lane) - 1ull));
                    if (rank < NSAMPLE) out[rank] = i;
                }
                taken += cnt;
            }
            const int sat = taken < NSAMPLE ? taken : NSAMPLE;
            if (lane >= sat && lane < NSAMPLE)
                out[lane] = (taken > 0) ? first : (NN - 1);
        }
        __syncthreads();

        // --- gather: 4 threads per sample ---
        {
            const int k  = pl >> 2;
            const int l4 = pl & 3;
            const int gi = sgidx[pr * 32 + k];
            const float* prow = points + ((size_t)b * NN + gi) * CC;
            float* fr = feats + (size_t)(pr * 32 + k) * 68;
            #pragma unroll
            for (int u = 0; u < 4; ++u)
                *(float4*)(fr + 4 + l4 * 16 + u * 4) =
                    *(const float4*)(prow + l4 * 16 + u * 4);
            if (l4 == 0) {
                const float* pxyz = xyz + ((size_t)b * NN + gi) * 3;
                fr[0] = pxyz[0] - cx;
                fr[1] = pxyz[1] - cy;
                fr[2] = pxyz[2] - cz;
            }
        }
        __syncthreads();

        // --- MLP layer 1: column c1 = lane, samples wi*16..wi*16+15 ---
        {
            const int c1 = lane;
            float w1r[67];
            #pragma unroll
            for (int j = 0; j < 67; ++j) w1r[j] = w1[c1 * 67 + j];
            const float bb1 = b1[c1];
            #pragma unroll
            for (int kk = 0; kk < 16; ++kk) {
                const int kr = wi * 16 + kk;
                const float* fr = feats + (size_t)(pr * 32 + kr) * 68;
                float acc = bb1;
                acc += fr[0] * w1r[0] + fr[1] * w1r[1] + fr[2] * w1r[2];
                #pragma unroll
                for (int j = 0; j < 64; j += 4) {
                    const float4 f = *(const float4*)(fr + 4 + j);
                    acc += f.x * w1r[3 + j] + f.y * w1r[4 + j]
                         + f.z * w1r[5 + j] + f.w * w1r[6 + j];
                }
                h1s[(size_t)(pr * 32 + kr) * 64 + c1] = fmaxf(acc, 0.0f);
            }
        }
        __syncthreads();

        // --- MLP layer 2 + max over all 32 samples (output o2 = pl) ---
        {
            float w2r[64];
            #pragma unroll
            for (int j = 0; j < 64; ++j) w2r[j] = w2[pl * 64 + j];
            const float bb2 = b2[pl];
            float mx = -INFINITY;
            #pragma unroll
            for (int kr = 0; kr < 32; ++kr) {
                const float* hr = h1s + (size_t)(pr * 32 + kr) * 64;
                float acc = bb2;
                #pragma unroll
                for (int j = 0; j < 64; j += 4) {
                    const float4 h = *(const float4*)(hr + j);
                    acc += h.x * w2r[j] + h.y * w2r[j + 1]
                         + h.z * w2r[j + 2] + h.w * w2r[j + 3];
                }
                mx = fmaxf(mx, fmaxf(acc, 0.0f));
            }
            new_points[(size_t)q * 128 + pl] = mx;
        }
        __syncthreads();   // LDS reused next round
    }
}

// ---------------------------------------------------------------------------
extern "C" void kernel_launch(void* const* d_in, const int* in_sizes, int n_in,
                              void* d_out, int out_size, void* d_ws, size_t ws_size,
                              hipStream_t stream) {
    const float* xyz    = (const float*)d_in[0];
    const float* points = (const float*)d_in[1];
    const float* w1     = (const float*)d_in[2];
    const float* b1     = (const float*)d_in[3];
    const float* w2     = (const float*)d_in[4];
    const float* b2     = (const float*)d_in[5];

    float* out_newxyz    = (float*)d_out;
    float* out_newpoints = (float*)d_out + (size_t)BB * NPOINT * 3;
    unsigned* prog   = (unsigned*)d_ws;                              // 16 B
    float4*   sortbuf = (float4*)((char*)d_ws + 1024);               // 1 MB

    (void)hipMemsetAsync(prog, 0, 4 * sizeof(unsigned), stream);

    const unsigned fused_lds = 148160;
    (void)hipFuncSetAttribute((const void*)fused_kernel,
                              hipFuncAttributeMaxDynamicSharedMemorySize,
                              (int)fused_lds);

    void* args[] = {(void*)&xyz, (void*)&points, (void*)&w1, (void*)&b1,
                    (void*)&w2, (void*)&b2, (void*)&out_newxyz,
                    (void*)&out_newpoints, (void*)&sortbuf, (void*)&prog};
    hipError_t err = hipLaunchCooperativeKernel(
        (const void*)fused_kernel, dim3(GRID_TOTAL), dim3(FPS_T),
        args, fused_lds, stream);
    if (err != hipSuccess) {
        // Fallback: plain launch. 200 blocks at 1 block/CU on 256 CUs are
        // co-resident in practice; blocks 0..3 dispatch first.
        fused_kernel<<<dim3(GRID_TOTAL), dim3(FPS_T), fused_lds, stream>>>(
            xyz, points, w1, b1, w2, b2, out_newxyz, out_newpoints,
            sortbuf, prog);
    }
}

// Round 15
// 1690.924 us; speedup vs baseline: 1.7904x; 1.7904x over previous
//
#include <hip/hip_runtime.h>

#define BB 4
#define NN 16384
#define CC 64
#define NPOINT 1024
#define NSAMPLE 32

#define FPS_T 1024
#define NCHUNK 256
#define NCELL 4096
#define GRID_TOTAL 200      // 4 fps + 196 consumer blocks (<= 256 CUs)
#define PROG_STRIDE 32      // one 128B cacheline per batch progress counter

#define REPEAT16(M) M(0) M(1) M(2) M(3) M(4) M(5) M(6) M(7) \
                    M(8) M(9) M(10) M(11) M(12) M(13) M(14) M(15)

// ---------------------------------------------------------------------------
// Fused cooperative kernel, publication-fixed (R14 post-mortem):
// Blocks 0..3  : R11-exact pruned FPS. Centroids go to LDS outc (no global
//                ops in the common iteration). Every 16 iters wave 15
//                flushes 16 centroids (48 relaxed agent stores, lanes 0..47)
//                + ONE release prog[b*32]. vmcnt drain amortized 1/16.
// Blocks 4..199: persistent consumers; poll prog (padded cacheline) with
//                s_sleep(64) -> negligible cross-XCD traffic; then ballq
//                (exact math) + gather + MLP for 8 queries (2 waves each).
// Exactness: identical to R11/R14 (fps+ballq contract(off) & ref op order;
// MLP FMA free). Release(prog) -> acquire(prog) orders centroid visibility.
// ---------------------------------------------------------------------------
__global__ __launch_bounds__(FPS_T, 4) void fused_kernel(
        const float* __restrict__ xyz, const float* __restrict__ points,
        const float* __restrict__ w1,  const float* __restrict__ b1,
        const float* __restrict__ w2,  const float* __restrict__ b2,
        float* __restrict__ new_xyz,   float* __restrict__ new_points,
        float4* __restrict__ sorted,   unsigned* __restrict__ prog) {
    extern __shared__ char smem_raw[];

    if (blockIdx.x < 4) {
        // ================= FPS producer (R11-exact + batched publish) =====
        #pragma clang fp contract(off)
        float2* sxy  = (float2*)smem_raw;                         // 131072 B
        int*    hist = (int*)(smem_raw + 131072);                 // 16384 B
        float*  outc = (float*)(smem_raw + 131072);               // alias
        float4* wbc  = (float4*)(smem_raw + 147456);              // [2][16]
        unsigned long long* slot = (unsigned long long*)(smem_raw + 147968);
        int*    wsum = (int*)(smem_raw + 148000);                 // [16]

        const int b    = blockIdx.x;
        const int tid  = threadIdx.x;
        const int lane = tid & 63;
        const int wv   = tid >> 6;
        const float* bx = xyz + (size_t)b * NN * 3;
        float4* sb = sorted + (size_t)b * NN;
        float* outg = new_xyz + (size_t)b * NPOINT * 3;

        // ---------- phase 0a: histogram ----------
        #pragma unroll
        for (int j = 0; j < 4; ++j) hist[j * FPS_T + tid] = 0;
        __syncthreads();

        #pragma unroll
        for (int j = 0; j < 16; ++j) {
            const int p = j * FPS_T + tid;
            const float x = bx[p * 3 + 0], y = bx[p * 3 + 1], z = bx[p * 3 + 2];
            int cx = (int)(x * 16.0f); cx = cx > 15 ? 15 : (cx < 0 ? 0 : cx);
            int cy = (int)(y * 16.0f); cy = cy > 15 ? 15 : (cy < 0 ? 0 : cy);
            int cz = (int)(z * 16.0f); cz = cz > 15 ? 15 : (cz < 0 ? 0 : cz);
            int code = 0;
            #pragma unroll
            for (int i = 0; i < 4; ++i)
                code |= (((cx >> i) & 1) << (3 * i)) |
                        (((cy >> i) & 1) << (3 * i + 1)) |
                        (((cz >> i) & 1) << (3 * i + 2));
            atomicAdd(&hist[code], 1);
        }
        __syncthreads();

        // ---------- phase 0b: exclusive scan ----------
        {
            const int h0 = hist[4 * tid + 0], h1 = hist[4 * tid + 1];
            const int h2 = hist[4 * tid + 2], h3 = hist[4 * tid + 3];
            const int s  = h0 + h1 + h2 + h3;
            int v = s;
            #pragma unroll
            for (int o = 1; o < 64; o <<= 1) {
                const int u = __shfl_up(v, o, 64);
                if (lane >= o) v += u;
            }
            if (lane == 63) wsum[wv] = v;
            __syncthreads();
            int base = 0;
            for (int w = 0; w < wv; ++w) base += wsum[w];
            const int e0 = base + v - s;
            hist[4 * tid + 0] = e0;
            hist[4 * tid + 1] = e0 + h0;
            hist[4 * tid + 2] = e0 + h0 + h1;
            hist[4 * tid + 3] = e0 + h0 + h1 + h2;
        }
        __syncthreads();

        // ---------- phase 0c: scatter ----------
        #pragma unroll
        for (int j = 0; j < 16; ++j) {
            const int p = j * FPS_T + tid;
            const float x = bx[p * 3 + 0], y = bx[p * 3 + 1], z = bx[p * 3 + 2];
            int cx = (int)(x * 16.0f); cx = cx > 15 ? 15 : (cx < 0 ? 0 : cx);
            int cy = (int)(y * 16.0f); cy = cy > 15 ? 15 : (cy < 0 ? 0 : cy);
            int cz = (int)(z * 16.0f); cz = cz > 15 ? 15 : (cz < 0 ? 0 : cz);
            int code = 0;
            #pragma unroll
            for (int i = 0; i < 4; ++i)
                code |= (((cx >> i) & 1) << (3 * i)) |
                        (((cy >> i) & 1) << (3 * i + 1)) |
                        (((cz >> i) & 1) << (3 * i + 2));
            const int slotg = atomicAdd(&hist[code], 1);
            sb[slotg]  = make_float4(x, y, z, __int_as_float(p));
            sxy[slotg] = make_float2(x, y);
        }
        __syncthreads();

        // ---------- phase 0d: per-chunk AABB + z/key preload ----------
#define DECLZ(k) float z##k; unsigned long long key##k;
        REPEAT16(DECLZ)
#undef DECLZ
        float abx0 = 0.f, aby0 = 0.f, abz0 = 0.f, abx1 = 0.f, aby1 = 0.f, abz1 = 0.f;

#define AABBPRE(k) { const int g = wv + ((k) << 4);                       \
        const float4 pt = sb[(g << 6) + lane];                            \
        z##k = pt.z;                                                      \
        key##k = (((unsigned long long)__float_as_uint(1e10f)) << 32) |   \
                 ((unsigned long long)(0x3FFFu -                          \
                        (unsigned)__float_as_int(pt.w)) << 4);            \
        float mnx = pt.x, mxx = pt.x, mny = pt.y, mxy = pt.y,             \
              mnz = pt.z, mxz = pt.z;                                     \
        _Pragma("unroll")                                                 \
        for (int m = 32; m >= 1; m >>= 1) {                               \
            mnx = fminf(mnx, __shfl_xor(mnx, m, 64));                     \
            mxx = fmaxf(mxx, __shfl_xor(mxx, m, 64));                     \
            mny = fminf(mny, __shfl_xor(mny, m, 64));                     \
            mxy = fmaxf(mxy, __shfl_xor(mxy, m, 64));                     \
            mnz = fminf(mnz, __shfl_xor(mnz, m, 64));                     \
            mxz = fmaxf(mxz, __shfl_xor(mxz, m, 64));                     \
        }                                                                 \
        if (lane == (k)) { abx0 = mnx; abx1 = mxx; aby0 = mny;            \
                           aby1 = mxy; abz0 = mnz; abz1 = mxz; } }
        REPEAT16(AABBPRE)
#undef AABBPRE
        if (tid < 4) slot[tid] = 0ull;
        __syncthreads();

        asm volatile("" : "+v"(z0), "+v"(z1), "+v"(z2),  "+v"(z3),
                          "+v"(z4), "+v"(z5), "+v"(z6),  "+v"(z7),
                          "+v"(z8), "+v"(z9), "+v"(z10), "+v"(z11),
                          "+v"(z12), "+v"(z13), "+v"(z14), "+v"(z15));

        // ---------- main loop ----------
        unsigned long long bkey = 0ull;
        int bestk = 0;
        int holder_ln = 0;
        float hx = 0.f, hy = 0.f, hz = 0.f;
        float cub = 1e10f;

        float ccx = bx[0], ccy = bx[1], ccz = bx[2];
        float prev_wd = 1e10f;

        for (int it = 0; it < NPOINT; ++it) {
            if (tid == 0) {
                outc[it * 3 + 0] = ccx;
                outc[it * 3 + 1] = ccy;
                outc[it * 3 + 2] = ccz;
            }

            // --- AABB prune + cub maintenance ---
            bool active = false;
            if (lane < 16) {
                const float dxl = fmaxf(fmaxf(abx0 - ccx, ccx - abx1), 0.0f);
                const float dyl = fmaxf(fmaxf(aby0 - ccy, ccy - aby1), 0.0f);
                const float dzl = fmaxf(fmaxf(abz0 - ccz, ccz - abz1), 0.0f);
                const float mind2 = dxl * dxl + dyl * dyl + dzl * dzl;
                const float bound = fminf(prev_wd, cub);
                active = !(mind2 > bound * 1.001f);
                if (active) {
                    const float dxm = fmaxf(ccx - abx0, abx1 - ccx);
                    const float dym = fmaxf(ccy - aby0, aby1 - ccy);
                    const float dzm = fmaxf(ccz - abz0, abz1 - ccz);
                    const float maxd2 = dxm * dxm + dym * dym + dzm * dzm;
                    cub = fminf(cub, maxd2);
                }
            }
            const unsigned amask = (unsigned)(__ballot(active) & 0xFFFFull);

            bool lredo = false;
#define UPD(k) if (amask & (1u << (k))) {                                 \
                const int g = wv + ((k) << 4);                            \
                const float2 xy = sxy[(g << 6) + lane];                   \
                const float dx = xy.x - ccx;                              \
                const float dy = xy.y - ccy;                              \
                const float dz = z##k - ccz;                              \
                const float t  = (dx * dx + dy * dy) + dz * dz;           \
                const float dold = __uint_as_float((unsigned)(key##k >> 32)); \
                if (t < dold) {                                           \
                    key##k = (((unsigned long long)__float_as_uint(t)) << 32) \
                             | (key##k & 0xFFFFFFFFull);                  \
                    lredo |= ((k) == bestk);                              \
                }                                                         \
            }
            if (amask & 0x000Fu) { UPD(0)  UPD(1)  UPD(2)  UPD(3)  }
            if (amask & 0x00F0u) { UPD(4)  UPD(5)  UPD(6)  UPD(7)  }
            if (amask & 0x0F00u) { UPD(8)  UPD(9)  UPD(10) UPD(11) }
            if (amask & 0xF000u) { UPD(12) UPD(13) UPD(14) UPD(15) }
#undef UPD

            if (lredo) {
                bkey = 0ull; bestk = 0;
#define LM(k) if (key##k > bkey) { bkey = key##k; bestk = (k); }
                REPEAT16(LM)
#undef LM
            }

            const unsigned long long rb = __ballot(lredo);
            if ((rb >> holder_ln) & 1ull) {
                unsigned long long m = bkey;
                #pragma unroll
                for (int s = 32; s >= 1; s >>= 1) {
                    const unsigned long long o = __shfl_xor(m, s, 64);
                    m = o > m ? o : m;
                }
                holder_ln = __ffsll((long long)__ballot(bkey == m)) - 1;
                if (lane == holder_ln) {
                    const float2 xy = sxy[((wv + (bestk << 4)) << 6) + lane];
                    float zz = z0;
#define ZS(k) zz = (bestk == (k)) ? z##k : zz;
                    REPEAT16(ZS)
#undef ZS
                    hx = xy.x; hy = xy.y; hz = zz;
                }
            }

            if (lane == holder_ln) {
                wbc[(it & 1) * 16 + wv] = make_float4(hx, hy, hz, 0.0f);
                atomicMax(&slot[it & 3], bkey | (unsigned long long)wv);
            }
            if (tid == 0) slot[(it + 1) & 3] = 0ull;
            __syncthreads();

            const unsigned long long wk = slot[it & 3];
            prev_wd = __uint_as_float((unsigned)(wk >> 32));
            const int wwv = (int)(wk & 0xFull);
            const float4 wf = wbc[(it & 1) * 16 + wwv];
            ccx = wf.x; ccy = wf.y; ccz = wf.z;

            // --- batched publication: every 16 iters, wave 15 flushes the
            // 16 centroids buffered in outc (it-15..it) + ONE release.
            // NOTE: outc[it] was written THIS iteration before the barrier;
            // the post-barrier read below is safe. vmcnt drain: wave 15 only.
            if ((it & 15) == 15 && wv == 15) {
                const int base = (it - 15) * 3;   // 48 floats
                if (lane < 48) {
                    __hip_atomic_store((unsigned*)(outg + base) + lane,
                                       __float_as_uint(outc[base + lane]),
                                       __ATOMIC_RELAXED,
                                       __HIP_MEMORY_SCOPE_AGENT);
                }
                if (lane == 0)
                    __hip_atomic_store(&prog[b * PROG_STRIDE],
                                       (unsigned)(it + 1), __ATOMIC_RELEASE,
                                       __HIP_MEMORY_SCOPE_AGENT);
            }
        }
        return;
    }

    // ================= Consumer blocks: ballq + MLP per query =============
    float* feats = (float*)smem_raw;                     // [8][32][68]
    float* h1s   = (float*)(smem_raw + 69632);           // [8][32][64]
    int*   sgidx = (int*)(smem_raw + 135168);            // [8][32]

    const int ci   = blockIdx.x - 4;
    const int NC   = (int)gridDim.x - 4;                 // 196
    const int tid  = threadIdx.x;
    const int lane = tid & 63;
    const int pr   = tid >> 7;                           // pair 0..7
    const int pl   = tid & 127;                          // lane within pair
    const int wi   = (tid >> 6) & 1;                     // wave within pair

    for (int q0 = ci * 8; q0 < BB * NPOINT; q0 += NC * 8) {
        const int b     = q0 >> 10;
        const int maxiq = (q0 + 7) & 1023;

        if (tid == 0) {
            while ((int)__hip_atomic_load(&prog[b * PROG_STRIDE],
                                          __ATOMIC_ACQUIRE,
                                          __HIP_MEMORY_SCOPE_AGENT) <= maxiq)
                __builtin_amdgcn_s_sleep(64);
        }
        __syncthreads();

        const int q = q0 + pr;
        const unsigned* cg = (const unsigned*)(new_xyz + (size_t)q * 3);
        const float cx = __uint_as_float(__hip_atomic_load(cg + 0,
                __ATOMIC_RELAXED, __HIP_MEMORY_SCOPE_AGENT));
        const float cy = __uint_as_float(__hip_atomic_load(cg + 1,
                __ATOMIC_RELAXED, __HIP_MEMORY_SCOPE_AGENT));
        const float cz = __uint_as_float(__hip_atomic_load(cg + 2,
                __ATOMIC_RELAXED, __HIP_MEMORY_SCOPE_AGENT));

        // --- ballq by the even wave of each pair (exact reference math) ---
        if (wi == 0) {
            #pragma clang fp contract(off)
            const float* bx = xyz + (size_t)b * NN * 3;
            const float rad2 = 0.04f;   // f32(0.2**2), NOT 0.2f*0.2f
            int* out  = sgidx + pr * 32;
            int taken = 0;
            int first = NN - 1;
            for (int chunk = 0; chunk < NN / 64 && taken < NSAMPLE; ++chunk) {
                const int   i  = chunk * 64 + lane;
                const float dx = cx - bx[i * 3 + 0];
                const float dy = cy - bx[i * 3 + 1];
                const float dz = cz - bx[i * 3 + 2];
                const float t  = dx * dx + dy * dy + dz * dz;
                const bool ok  = !(t > rad2);
                const unsigned long long m = __ballot(ok);
                const int cnt = __popcll(m);
                if (taken == 0 && cnt > 0)
                    first = chunk * 64 + (__ffsll((long long)m) - 1);
                if (ok) {
                    const int rank = taken + __popcll(m & ((1ull << lane) - 1ull));
                    if (rank < NSAMPLE) out[rank] = i;
                }
                taken += cnt;
            }
            const int sat = taken < NSAMPLE ? taken : NSAMPLE;
            if (lane >= sat && lane < NSAMPLE)
                out[lane] = (taken > 0) ? first : (NN - 1);
        }
        __syncthreads();

        // --- gather: 4 threads per sample ---
        {
            const int k  = pl >> 2;
            const int l4 = pl & 3;
            const int gi = sgidx[pr * 32 + k];
            const float* prow = points + ((size_t)b * NN + gi) * CC;
            float* fr = feats + (size_t)(pr * 32 + k) * 68;
            #pragma unroll
            for (int u = 0; u < 4; ++u)
                *(float4*)(fr + 4 + l4 * 16 + u * 4) =
                    *(const float4*)(prow + l4 * 16 + u * 4);
            if (l4 == 0) {
                const float* pxyz = xyz + ((size_t)b * NN + gi) * 3;
                fr[0] = pxyz[0] - cx;
                fr[1] = pxyz[1] - cy;
                fr[2] = pxyz[2] - cz;
            }
        }
        __syncthreads();

        // --- MLP layer 1 ---
        {
            const int c1 = lane;
            float w1r[67];
            #pragma unroll
            for (int j = 0; j < 67; ++j) w1r[j] = w1[c1 * 67 + j];
            const float bb1 = b1[c1];
            #pragma unroll
            for (int kk = 0; kk < 16; ++kk) {
                const int kr = wi * 16 + kk;
                const float* fr = feats + (size_t)(pr * 32 + kr) * 68;
                float acc = bb1;
                acc += fr[0] * w1r[0] + fr[1] * w1r[1] + fr[2] * w1r[2];
                #pragma unroll
                for (int j = 0; j < 64; j += 4) {
                    const float4 f = *(const float4*)(fr + 4 + j);
                    acc += f.x * w1r[3 + j] + f.y * w1r[4 + j]
                         + f.z * w1r[5 + j] + f.w * w1r[6 + j];
                }
                h1s[(size_t)(pr * 32 + kr) * 64 + c1] = fmaxf(acc, 0.0f);
            }
        }
        __syncthreads();

        // --- MLP layer 2 + max over 32 samples ---
        {
            float w2r[64];
            #pragma unroll
            for (int j = 0; j < 64; ++j) w2r[j] = w2[pl * 64 + j];
            const float bb2 = b2[pl];
            float mx = -INFINITY;
            #pragma unroll
            for (int kr = 0; kr < 32; ++kr) {
                const float* hr = h1s + (size_t)(pr * 32 + kr) * 64;
                float acc = bb2;
                #pragma unroll
                for (int j = 0; j < 64; j += 4) {
                    const float4 h = *(const float4*)(hr + j);
                    acc += h.x * w2r[j] + h.y * w2r[j + 1]
                         + h.z * w2r[j + 2] + h.w * w2r[j + 3];
                }
                mx = fmaxf(mx, fmaxf(acc, 0.0f));
            }
            new_points[(size_t)q * 128 + pl] = mx;
        }
        __syncthreads();   // LDS reused next round
    }
}

// ---------------------------------------------------------------------------
extern "C" void kernel_launch(void* const* d_in, const int* in_sizes, int n_in,
                              void* d_out, int out_size, void* d_ws, size_t ws_size,
                              hipStream_t stream) {
    const float* xyz    = (const float*)d_in[0];
    const float* points = (const float*)d_in[1];
    const float* w1     = (const float*)d_in[2];
    const float* b1     = (const float*)d_in[3];
    const float* w2     = (const float*)d_in[4];
    const float* b2     = (const float*)d_in[5];

    float* out_newxyz    = (float*)d_out;
    float* out_newpoints = (float*)d_out + (size_t)BB * NPOINT * 3;
    unsigned* prog   = (unsigned*)d_ws;                      // 4*32 u32, padded
    float4*   sortbuf = (float4*)((char*)d_ws + 4096);       // 1 MB

    (void)hipMemsetAsync(prog, 0, BB * PROG_STRIDE * sizeof(unsigned), stream);

    const unsigned fused_lds = 148160;
    (void)hipFuncSetAttribute((const void*)fused_kernel,
                              hipFuncAttributeMaxDynamicSharedMemorySize,
                              (int)fused_lds);

    void* args[] = {(void*)&xyz, (void*)&points, (void*)&w1, (void*)&b1,
                    (void*)&w2, (void*)&b2, (void*)&out_newxyz,
                    (void*)&out_newpoints, (void*)&sortbuf, (void*)&prog};
    hipError_t err = hipLaunchCooperativeKernel(
        (const void*)fused_kernel, dim3(GRID_TOTAL), dim3(FPS_T),
        args, fused_lds, stream);
    if (err != hipSuccess) {
        // Fallback: plain launch. 200 blocks at 1 block/CU on 256 CUs are
        // co-resident; blocks 0..3 dispatch first.
        fused_kernel<<<dim3(GRID_TOTAL), dim3(FPS_T), fused_lds, stream>>>(
            xyz, points, w1, b1, w2, b2, out_newxyz, out_newpoints,
            sortbuf, prog);
    }
}

// Round 16
// 1664.688 us; speedup vs baseline: 1.8186x; 1.0158x over previous
//
#include <hip/hip_runtime.h>

#define BB 4
#define NN 16384
#define CC 64
#define NPOINT 1024
#define NSAMPLE 32

#define FPS_T 1024
#define NCHUNK 256
#define NCELL 4096
#define GRID_TOTAL 200      // 4 fps + 196 consumer blocks (<= 256 CUs)
#define PROG_STRIDE 32      // one 128B cacheline per batch progress counter

#define REPEAT16(M) M(0) M(1) M(2) M(3) M(4) M(5) M(6) M(7) \
                    M(8) M(9) M(10) M(11) M(12) M(13) M(14) M(15)

// ---------------------------------------------------------------------------
// Fused cooperative kernel, deferred-release publication (R15 post-mortem):
// Blocks 0..3  : R11-EXACT pruned FPS (per-iter pin, single-slot atomicMax,
//                wbc read — the measured 1.38us/iter optimum). Centroids
//                buffered in LDS outc. Flush every 16 iters by wave 15:
//                (a) release prog = it-15 FIRST (vmcnt covers only stores
//                issued >=16 iters ago -> zero wait), then (b) 48 relaxed
//                agent stores of the current batch. Final drain+release
//                (prog=1024) post-loop. Publication ~zero-cost.
// Blocks 4..199: persistent consumers; poll padded prog with s_sleep(100);
//                ballq (exact ref math) + gather + MLP for 8 queries each
//                round (2 waves/query). Release->acquire orders visibility.
// Exactness: fps+ballq contract(off) & reference op order; first-index
// tie-breaks exact; MLP FMA free (reference einsum -> GEMM).
// ---------------------------------------------------------------------------
__global__ __launch_bounds__(FPS_T, 4) void fused_kernel(
        const float* __restrict__ xyz, const float* __restrict__ points,
        const float* __restrict__ w1,  const float* __restrict__ b1,
        const float* __restrict__ w2,  const float* __restrict__ b2,
        float* __restrict__ new_xyz,   float* __restrict__ new_points,
        float4* __restrict__ sorted,   unsigned* __restrict__ prog) {
    extern __shared__ char smem_raw[];

    if (blockIdx.x < 4) {
        // ================= FPS producer (R11-exact + deferred publish) ====
        #pragma clang fp contract(off)
        float2* sxy  = (float2*)smem_raw;                         // 131072 B
        int*    hist = (int*)(smem_raw + 131072);                 // 16384 B
        float*  outc = (float*)(smem_raw + 131072);               // alias
        float4* wbc  = (float4*)(smem_raw + 147456);              // [2][16]
        unsigned long long* slot = (unsigned long long*)(smem_raw + 147968);
        int*    wsum = (int*)(smem_raw + 148000);                 // [16]

        const int b    = blockIdx.x;
        const int tid  = threadIdx.x;
        const int lane = tid & 63;
        const int wv   = tid >> 6;
        const float* bx = xyz + (size_t)b * NN * 3;
        float4* sb = sorted + (size_t)b * NN;
        float* outg = new_xyz + (size_t)b * NPOINT * 3;

        // ---------- phase 0a: histogram ----------
        #pragma unroll
        for (int j = 0; j < 4; ++j) hist[j * FPS_T + tid] = 0;
        __syncthreads();

        #pragma unroll
        for (int j = 0; j < 16; ++j) {
            const int p = j * FPS_T + tid;
            const float x = bx[p * 3 + 0], y = bx[p * 3 + 1], z = bx[p * 3 + 2];
            int cx = (int)(x * 16.0f); cx = cx > 15 ? 15 : (cx < 0 ? 0 : cx);
            int cy = (int)(y * 16.0f); cy = cy > 15 ? 15 : (cy < 0 ? 0 : cy);
            int cz = (int)(z * 16.0f); cz = cz > 15 ? 15 : (cz < 0 ? 0 : cz);
            int code = 0;
            #pragma unroll
            for (int i = 0; i < 4; ++i)
                code |= (((cx >> i) & 1) << (3 * i)) |
                        (((cy >> i) & 1) << (3 * i + 1)) |
                        (((cz >> i) & 1) << (3 * i + 2));
            atomicAdd(&hist[code], 1);
        }
        __syncthreads();

        // ---------- phase 0b: exclusive scan ----------
        {
            const int h0 = hist[4 * tid + 0], h1 = hist[4 * tid + 1];
            const int h2 = hist[4 * tid + 2], h3 = hist[4 * tid + 3];
            const int s  = h0 + h1 + h2 + h3;
            int v = s;
            #pragma unroll
            for (int o = 1; o < 64; o <<= 1) {
                const int u = __shfl_up(v, o, 64);
                if (lane >= o) v += u;
            }
            if (lane == 63) wsum[wv] = v;
            __syncthreads();
            int base = 0;
            for (int w = 0; w < wv; ++w) base += wsum[w];
            const int e0 = base + v - s;
            hist[4 * tid + 0] = e0;
            hist[4 * tid + 1] = e0 + h0;
            hist[4 * tid + 2] = e0 + h0 + h1;
            hist[4 * tid + 3] = e0 + h0 + h1 + h2;
        }
        __syncthreads();

        // ---------- phase 0c: scatter ----------
        #pragma unroll
        for (int j = 0; j < 16; ++j) {
            const int p = j * FPS_T + tid;
            const float x = bx[p * 3 + 0], y = bx[p * 3 + 1], z = bx[p * 3 + 2];
            int cx = (int)(x * 16.0f); cx = cx > 15 ? 15 : (cx < 0 ? 0 : cx);
            int cy = (int)(y * 16.0f); cy = cy > 15 ? 15 : (cy < 0 ? 0 : cy);
            int cz = (int)(z * 16.0f); cz = cz > 15 ? 15 : (cz < 0 ? 0 : cz);
            int code = 0;
            #pragma unroll
            for (int i = 0; i < 4; ++i)
                code |= (((cx >> i) & 1) << (3 * i)) |
                        (((cy >> i) & 1) << (3 * i + 1)) |
                        (((cz >> i) & 1) << (3 * i + 2));
            const int slotg = atomicAdd(&hist[code], 1);
            sb[slotg]  = make_float4(x, y, z, __int_as_float(p));
            sxy[slotg] = make_float2(x, y);
        }
        __syncthreads();

        // ---------- phase 0d: per-chunk AABB + z/key preload ----------
#define DECLZ(k) float z##k; unsigned long long key##k;
        REPEAT16(DECLZ)
#undef DECLZ
        float abx0 = 0.f, aby0 = 0.f, abz0 = 0.f, abx1 = 0.f, aby1 = 0.f, abz1 = 0.f;

#define AABBPRE(k) { const int g = wv + ((k) << 4);                       \
        const float4 pt = sb[(g << 6) + lane];                            \
        z##k = pt.z;                                                      \
        key##k = (((unsigned long long)__float_as_uint(1e10f)) << 32) |   \
                 ((unsigned long long)(0x3FFFu -                          \
                        (unsigned)__float_as_int(pt.w)) << 4);            \
        float mnx = pt.x, mxx = pt.x, mny = pt.y, mxy = pt.y,             \
              mnz = pt.z, mxz = pt.z;                                     \
        _Pragma("unroll")                                                 \
        for (int m = 32; m >= 1; m >>= 1) {                               \
            mnx = fminf(mnx, __shfl_xor(mnx, m, 64));                     \
            mxx = fmaxf(mxx, __shfl_xor(mxx, m, 64));                     \
            mny = fminf(mny, __shfl_xor(mny, m, 64));                     \
            mxy = fmaxf(mxy, __shfl_xor(mxy, m, 64));                     \
            mnz = fminf(mnz, __shfl_xor(mnz, m, 64));                     \
            mxz = fmaxf(mxz, __shfl_xor(mxz, m, 64));                     \
        }                                                                 \
        if (lane == (k)) { abx0 = mnx; abx1 = mxx; aby0 = mny;            \
                           aby1 = mxy; abz0 = mnz; abz1 = mxz; } }
        REPEAT16(AABBPRE)
#undef AABBPRE
        if (tid < 4) slot[tid] = 0ull;
        __syncthreads();

        // ---------- main loop (R11-exact) ----------
        unsigned long long bkey = 0ull;
        int bestk = 0;
        int holder_ln = 0;
        float hx = 0.f, hy = 0.f, hz = 0.f;
        float cub = 1e10f;

        float ccx = bx[0], ccy = bx[1], ccz = bx[2];
        float prev_wd = 1e10f;

        for (int it = 0; it < NPOINT; ++it) {
            asm volatile("" : "+v"(z0), "+v"(z1), "+v"(z2),  "+v"(z3),
                              "+v"(z4), "+v"(z5), "+v"(z6),  "+v"(z7),
                              "+v"(z8), "+v"(z9), "+v"(z10), "+v"(z11),
                              "+v"(z12), "+v"(z13), "+v"(z14), "+v"(z15));

            if (tid == 0) {
                outc[it * 3 + 0] = ccx;
                outc[it * 3 + 1] = ccy;
                outc[it * 3 + 2] = ccz;
            }

            // --- AABB prune + cub maintenance ---
            bool active = false;
            if (lane < 16) {
                const float dxl = fmaxf(fmaxf(abx0 - ccx, ccx - abx1), 0.0f);
                const float dyl = fmaxf(fmaxf(aby0 - ccy, ccy - aby1), 0.0f);
                const float dzl = fmaxf(fmaxf(abz0 - ccz, ccz - abz1), 0.0f);
                const float mind2 = dxl * dxl + dyl * dyl + dzl * dzl;
                const float bound = fminf(prev_wd, cub);
                active = !(mind2 > bound * 1.001f);
                if (active) {
                    const float dxm = fmaxf(ccx - abx0, abx1 - ccx);
                    const float dym = fmaxf(ccy - aby0, aby1 - ccy);
                    const float dzm = fmaxf(ccz - abz0, abz1 - ccz);
                    const float maxd2 = dxm * dxm + dym * dym + dzm * dzm;
                    cub = fminf(cub, maxd2);
                }
            }
            const unsigned amask = (unsigned)(__ballot(active) & 0xFFFFull);

            bool lredo = false;
#define UPD(k) if (amask & (1u << (k))) {                                 \
                const int g = wv + ((k) << 4);                            \
                const float2 xy = sxy[(g << 6) + lane];                   \
                const float dx = xy.x - ccx;                              \
                const float dy = xy.y - ccy;                              \
                const float dz = z##k - ccz;                              \
                const float t  = (dx * dx + dy * dy) + dz * dz;           \
                const float dold = __uint_as_float((unsigned)(key##k >> 32)); \
                if (t < dold) {                                           \
                    key##k = (((unsigned long long)__float_as_uint(t)) << 32) \
                             | (key##k & 0xFFFFFFFFull);                  \
                    lredo |= ((k) == bestk);                              \
                }                                                         \
            }
            if (amask & 0x000Fu) { UPD(0)  UPD(1)  UPD(2)  UPD(3)  }
            if (amask & 0x00F0u) { UPD(4)  UPD(5)  UPD(6)  UPD(7)  }
            if (amask & 0x0F00u) { UPD(8)  UPD(9)  UPD(10) UPD(11) }
            if (amask & 0xF000u) { UPD(12) UPD(13) UPD(14) UPD(15) }
#undef UPD

            if (lredo) {
                bkey = 0ull; bestk = 0;
#define LM(k) if (key##k > bkey) { bkey = key##k; bestk = (k); }
                REPEAT16(LM)
#undef LM
            }

            const unsigned long long rb = __ballot(lredo);
            if ((rb >> holder_ln) & 1ull) {
                unsigned long long m = bkey;
                #pragma unroll
                for (int s = 32; s >= 1; s >>= 1) {
                    const unsigned long long o = __shfl_xor(m, s, 64);
                    m = o > m ? o : m;
                }
                holder_ln = __ffsll((long long)__ballot(bkey == m)) - 1;
                if (lane == holder_ln) {
                    const float2 xy = sxy[((wv + (bestk << 4)) << 6) + lane];
                    float zz = z0;
#define ZS(k) zz = (bestk == (k)) ? z##k : zz;
                    REPEAT16(ZS)
#undef ZS
                    hx = xy.x; hy = xy.y; hz = zz;
                }
            }

            if (lane == holder_ln) {
                wbc[(it & 1) * 16 + wv] = make_float4(hx, hy, hz, 0.0f);
                atomicMax(&slot[it & 3], bkey | (unsigned long long)wv);
            }
            if (tid == 0) slot[(it + 1) & 3] = 0ull;
            __syncthreads();

            const unsigned long long wk = slot[it & 3];
            prev_wd = __uint_as_float((unsigned)(wk >> 32));
            const int wwv = (int)(wk & 0xFull);
            const float4 wf = wbc[(it & 1) * 16 + wwv];
            ccx = wf.x; ccy = wf.y; ccz = wf.z;

            // --- deferred-release publication (every 16 iters, wave 15):
            // release FIRST (covers the batch stored at the PREVIOUS flush;
            // its stores retired ~22us ago -> implicit vmcnt wait is zero),
            // then fire-and-forget the current batch's relaxed stores.
            if ((it & 15) == 15 && wv == 15) {
                if (lane == 0 && it > 15)
                    __hip_atomic_store(&prog[b * PROG_STRIDE],
                                       (unsigned)(it - 15), __ATOMIC_RELEASE,
                                       __HIP_MEMORY_SCOPE_AGENT);
                const int base = (it - 15) * 3;   // 48 floats
                if (lane < 48)
                    __hip_atomic_store((unsigned*)(outg + base) + lane,
                                       __float_as_uint(outc[base + lane]),
                                       __ATOMIC_RELAXED,
                                       __HIP_MEMORY_SCOPE_AGENT);
            }
        }

        // final publication: drain (implicit in release) + prog = 1024
        if (wv == 15 && lane == 0)
            __hip_atomic_store(&prog[b * PROG_STRIDE], (unsigned)NPOINT,
                               __ATOMIC_RELEASE, __HIP_MEMORY_SCOPE_AGENT);
        return;
    }

    // ================= Consumer blocks: ballq + MLP per query =============
    float* feats = (float*)smem_raw;                     // [8][32][68]
    float* h1s   = (float*)(smem_raw + 69632);           // [8][32][64]
    int*   sgidx = (int*)(smem_raw + 135168);            // [8][32]

    const int ci   = blockIdx.x - 4;
    const int NC   = (int)gridDim.x - 4;                 // 196
    const int tid  = threadIdx.x;
    const int lane = tid & 63;
    const int pr   = tid >> 7;                           // pair 0..7
    const int pl   = tid & 127;                          // lane within pair
    const int wi   = (tid >> 6) & 1;                     // wave within pair

    for (int q0 = ci * 8; q0 < BB * NPOINT; q0 += NC * 8) {
        const int b     = q0 >> 10;
        const int maxiq = (q0 + 7) & 1023;

        if (tid == 0) {
            while ((int)__hip_atomic_load(&prog[b * PROG_STRIDE],
                                          __ATOMIC_ACQUIRE,
                                          __HIP_MEMORY_SCOPE_AGENT) <= maxiq)
                __builtin_amdgcn_s_sleep(100);
        }
        __syncthreads();

        const int q = q0 + pr;
        const unsigned* cg = (const unsigned*)(new_xyz + (size_t)q * 3);
        const float cx = __uint_as_float(__hip_atomic_load(cg + 0,
                __ATOMIC_RELAXED, __HIP_MEMORY_SCOPE_AGENT));
        const float cy = __uint_as_float(__hip_atomic_load(cg + 1,
                __ATOMIC_RELAXED, __HIP_MEMORY_SCOPE_AGENT));
        const float cz = __uint_as_float(__hip_atomic_load(cg + 2,
                __ATOMIC_RELAXED, __HIP_MEMORY_SCOPE_AGENT));

        // --- ballq by the even wave of each pair (exact reference math) ---
        if (wi == 0) {
            #pragma clang fp contract(off)
            const float* bx = xyz + (size_t)b * NN * 3;
            const float rad2 = 0.04f;   // f32(0.2**2), NOT 0.2f*0.2f
            int* out  = sgidx + pr * 32;
            int taken = 0;
            int first = NN - 1;
            for (int chunk = 0; chunk < NN / 64 && taken < NSAMPLE; ++chunk) {
                const int   i  = chunk * 64 + lane;
                const float dx = cx - bx[i * 3 + 0];
                const float dy = cy - bx[i * 3 + 1];
                const float dz = cz - bx[i * 3 + 2];
                const float t  = dx * dx + dy * dy + dz * dz;
                const bool ok  = !(t > rad2);
                const unsigned long long m = __ballot(ok);
                const int cnt = __popcll(m);
                if (taken == 0 && cnt > 0)
                    first = chunk * 64 + (__ffsll((long long)m) - 1);
                if (ok) {
                    const int rank = taken + __popcll(m & ((1ull << lane) - 1ull));
                    if (rank < NSAMPLE) out[rank] = i;
                }
                taken += cnt;
            }
            const int sat = taken < NSAMPLE ? taken : NSAMPLE;
            if (lane >= sat && lane < NSAMPLE)
                out[lane] = (taken > 0) ? first : (NN - 1);
        }
        __syncthreads();

        // --- gather: 4 threads per sample ---
        {
            const int k  = pl >> 2;
            const int l4 = pl & 3;
            const int gi = sgidx[pr * 32 + k];
            const float* prow = points + ((size_t)b * NN + gi) * CC;
            float* fr = feats + (size_t)(pr * 32 + k) * 68;
            #pragma unroll
            for (int u = 0; u < 4; ++u)
                *(float4*)(fr + 4 + l4 * 16 + u * 4) =
                    *(const float4*)(prow + l4 * 16 + u * 4);
            if (l4 == 0) {
                const float* pxyz = xyz + ((size_t)b * NN + gi) * 3;
                fr[0] = pxyz[0] - cx;
                fr[1] = pxyz[1] - cy;
                fr[2] = pxyz[2] - cz;
            }
        }
        __syncthreads();

        // --- MLP layer 1 ---
        {
            const int c1 = lane;
            float w1r[67];
            #pragma unroll
            for (int j = 0; j < 67; ++j) w1r[j] = w1[c1 * 67 + j];
            const float bb1 = b1[c1];
            #pragma unroll
            for (int kk = 0; kk < 16; ++kk) {
                const int kr = wi * 16 + kk;
                const float* fr = feats + (size_t)(pr * 32 + kr) * 68;
                float acc = bb1;
                acc += fr[0] * w1r[0] + fr[1] * w1r[1] + fr[2] * w1r[2];
                #pragma unroll
                for (int j = 0; j < 64; j += 4) {
                    const float4 f = *(const float4*)(fr + 4 + j);
                    acc += f.x * w1r[3 + j] + f.y * w1r[4 + j]
                         + f.z * w1r[5 + j] + f.w * w1r[6 + j];
                }
                h1s[(size_t)(pr * 32 + kr) * 64 + c1] = fmaxf(acc, 0.0f);
            }
        }
        __syncthreads();

        // --- MLP layer 2 + max over 32 samples ---
        {
            float w2r[64];
            #pragma unroll
            for (int j = 0; j < 64; ++j) w2r[j] = w2[pl * 64 + j];
            const float bb2 = b2[pl];
            float mx = -INFINITY;
            #pragma unroll
            for (int kr = 0; kr < 32; ++kr) {
                const float* hr = h1s + (size_t)(pr * 32 + kr) * 64;
                float acc = bb2;
                #pragma unroll
                for (int j = 0; j < 64; j += 4) {
                    const float4 h = *(const float4*)(hr + j);
                    acc += h.x * w2r[j] + h.y * w2r[j + 1]
                         + h.z * w2r[j + 2] + h.w * w2r[j + 3];
                }
                mx = fmaxf(mx, fmaxf(acc, 0.0f));
            }
            new_points[(size_t)q * 128 + pl] = mx;
        }
        __syncthreads();   // LDS reused next round
    }
}

// ---------------------------------------------------------------------------
extern "C" void kernel_launch(void* const* d_in, const int* in_sizes, int n_in,
                              void* d_out, int out_size, void* d_ws, size_t ws_size,
                              hipStream_t stream) {
    const float* xyz    = (const float*)d_in[0];
    const float* points = (const float*)d_in[1];
    const float* w1     = (const float*)d_in[2];
    const float* b1     = (const float*)d_in[3];
    const float* w2     = (const float*)d_in[4];
    const float* b2     = (const float*)d_in[5];

    float* out_newxyz    = (float*)d_out;
    float* out_newpoints = (float*)d_out + (size_t)BB * NPOINT * 3;
    unsigned* prog   = (unsigned*)d_ws;                      // 4*32 u32, padded
    float4*   sortbuf = (float4*)((char*)d_ws + 4096);       // 1 MB

    (void)hipMemsetAsync(prog, 0, BB * PROG_STRIDE * sizeof(unsigned), stream);

    const unsigned fused_lds = 148160;
    (void)hipFuncSetAttribute((const void*)fused_kernel,
                              hipFuncAttributeMaxDynamicSharedMemorySize,
                              (int)fused_lds);

    void* args[] = {(void*)&xyz, (void*)&points, (void*)&w1, (void*)&b1,
                    (void*)&w2, (void*)&b2, (void*)&out_newxyz,
                    (void*)&out_newpoints, (void*)&sortbuf, (void*)&prog};
    hipError_t err = hipLaunchCooperativeKernel(
        (const void*)fused_kernel, dim3(GRID_TOTAL), dim3(FPS_T),
        args, fused_lds, stream);
    if (err != hipSuccess) {
        // Fallback: plain launch. 200 blocks, 1 block/CU (LDS-bound) on
        // 256 CUs are co-resident; blocks 0..3 dispatch first.
        fused_kernel<<<dim3(GRID_TOTAL), dim3(FPS_T), fused_lds, stream>>>(
            xyz, points, w1, b1, w2, b2, out_newxyz, out_newpoints,
            sortbuf, prog);
    }
}